// Round 3
// baseline (311.505 us; speedup 1.0000x reference)
//
#include <hip/hip_runtime.h>

typedef unsigned short u16;
typedef unsigned int u32;
typedef __attribute__((ext_vector_type(8))) short bf16x8;
typedef __attribute__((ext_vector_type(4))) float f32x4;
typedef __attribute__((ext_vector_type(4))) unsigned short u16x4;

#define NKV 144   // 128 V-dims + 1 ones-row (Ksum) + 15 zero pad (9 MFMA n-frags)

__device__ __forceinline__ u16 f2b(float f){
  u32 i = __float_as_uint(f);
  u32 r = (i + 0x7FFFu + ((i >> 16) & 1u)) >> 16;
  return (u16)r;
}

__device__ __forceinline__ void cp16(const void* g, void* l){
  __builtin_amdgcn_global_load_lds(
      (__attribute__((address_space(1))) void*)(const_cast<void*>(g)),
      (__attribute__((address_space(3))) void*)(l), 16, 0, 0);
}

// Stage rows x 64 bf16 (rows*128 bytes) into LDS. Linear LDS dest (required by
// global_load_lds); XOR 16B-chunk swizzle applied on the GLOBAL source so that
// swizzled reads below are conflict-light (2-way max).
__device__ __forceinline__ void stage_tile(const u16* g, int stride_el, int rows,
                                           u16* lds, int tid){
  const char* gc = (const char*)g;
  char* lc = (char*)lds;
  const int total = rows * 128;
  for (int off = tid * 16; off < total; off += 4096){
    int row = off >> 7;
    int chunk = (off >> 4) & 7;
    int gchunk = chunk ^ (row & 7);
    cp16(gc + (size_t)row * (size_t)(stride_el * 2) + gchunk * 16, lc + off);
  }
}

// Fragment read: logical (row, k-chunk) -> swizzled physical chunk.
__device__ __forceinline__ bf16x8 frag_ld(const u16* lds, int row, int kk, int lane){
  int chunk = (kk >> 3) + (lane >> 4);
  int pc = chunk ^ (row & 7);
  return *(const bf16x8*)(lds + row * 64 + pc * 8);
}

// ---- core A: 4 waves in 2x2, each wave 64x64 (4x4 frags), BM=BN=128, BK=64 ----
__device__ __forceinline__ void core22(const u16* Ag, int As, const u16* Bg, int Bs,
                                       int ksteps, u16* ldsA, u16* ldsB,
                                       f32x4 (&acc)[4][4]){
  const int tid = threadIdx.x, lane = tid & 63, w = tid >> 6;
  const int wm = (w >> 1) * 64, wn = (w & 1) * 64;
  for (int t = 0; t < ksteps; ++t){
    stage_tile(Ag + t * 64, As, 128, ldsA, tid);
    stage_tile(Bg + t * 64, Bs, 128, ldsB, tid);
    __syncthreads();
#pragma unroll
    for (int kk = 0; kk < 64; kk += 32){
      bf16x8 af[4], bfr[4];
#pragma unroll
      for (int i = 0; i < 4; ++i) af[i]  = frag_ld(ldsA, wm + i * 16 + (lane & 15), kk, lane);
#pragma unroll
      for (int i = 0; i < 4; ++i) bfr[i] = frag_ld(ldsB, wn + i * 16 + (lane & 15), kk, lane);
#pragma unroll
      for (int m = 0; m < 4; ++m)
#pragma unroll
        for (int n = 0; n < 4; ++n)
          acc[m][n] = __builtin_amdgcn_mfma_f32_16x16x32_bf16(af[m], bfr[n], acc[m][n], 0, 0, 0);
    }
    __syncthreads();
  }
}

// ---- core B: 4 waves m-stacked, each wave 32x144 (2x9 frags), BM=128, BN=144 ----
__device__ __forceinline__ void core41(const u16* Ag, int As, const u16* Bg, int Bs,
                                       int ksteps, u16* ldsA, u16* ldsB,
                                       f32x4 (&acc)[2][9]){
  const int tid = threadIdx.x, lane = tid & 63, w = tid >> 6;
  const int wm = w * 32;
  for (int t = 0; t < ksteps; ++t){
    stage_tile(Ag + t * 64, As, 128, ldsA, tid);
    stage_tile(Bg + t * 64, Bs, NKV, ldsB, tid);
    __syncthreads();
#pragma unroll
    for (int kk = 0; kk < 64; kk += 32){
      bf16x8 af[2], bfr[9];
#pragma unroll
      for (int i = 0; i < 2; ++i) af[i]  = frag_ld(ldsA, wm + i * 16 + (lane & 15), kk, lane);
#pragma unroll
      for (int i = 0; i < 9; ++i) bfr[i] = frag_ld(ldsB, i * 16 + (lane & 15), kk, lane);
#pragma unroll
      for (int m = 0; m < 2; ++m)
#pragma unroll
        for (int n = 0; n < 9; ++n)
          acc[m][n] = __builtin_amdgcn_mfma_f32_16x16x32_bf16(af[m], bfr[n], acc[m][n], 0, 0, 0);
    }
    __syncthreads();
  }
}

// ---- prep kernels ----
__global__ void k_cast(const float* __restrict__ src, u16* __restrict__ dst, int n4){
  int stride = gridDim.x * blockDim.x;
  for (int i = blockIdx.x * blockDim.x + threadIdx.x; i < n4; i += stride){
    float4 v = ((const float4*)src)[i];
    u16x4 o; o[0] = f2b(v.x); o[1] = f2b(v.y); o[2] = f2b(v.z); o[3] = f2b(v.w);
    ((u16x4*)dst)[i] = o;
  }
}

// dst[C][R] bf16 = transpose(src[R][C] f32)
__global__ void k_tc(const float* __restrict__ src, u16* __restrict__ dst, int R, int C){
  __shared__ float t[64][65];
  const int c0 = blockIdx.x * 64, r0 = blockIdx.y * 64;
  const int tid = threadIdx.x;
  for (int i = tid; i < 4096; i += 256){
    int r = i >> 6, c = i & 63;
    t[r][c] = src[(size_t)(r0 + r) * C + c0 + c];
  }
  __syncthreads();
  for (int i = tid; i < 4096; i += 256){
    int r = i >> 6, c = i & 63;
    dst[(size_t)(c0 + r) * R + r0 + c] = f2b(t[c][r]);
  }
}

// VT pad rows: row 128 = 1.0 (Ksum via ones column), rows 129..143 = 0
__global__ void k_vtinit(u16* __restrict__ VT){
  const int total = 32 * 16 * 4096 / 4;
  int stride = gridDim.x * blockDim.x;
  for (int i = blockIdx.x * blockDim.x + threadIdx.x; i < total; i += stride){
    int idx = i * 4;
    int s   = idx & 4095;
    int rem = idx >> 12;
    int row = 128 + (rem & 15);
    int bh  = rem >> 4;
    u16 val = (row == 128) ? (u16)0x3F80 : (u16)0;
    u16x4 o = {val, val, val, val};
    *(u16x4*)&VT[((size_t)bh * NKV + row) * 4096 + s] = o;
  }
}

// ---- K2: QKV projection. grid (128 mtiles, 24 ntiles); ntile -> (sect,h) ----
__global__ __launch_bounds__(256, 2)
void k_qkv(const u16* __restrict__ xb, const u16* __restrict__ WqT,
           const u16* __restrict__ WkT, const u16* __restrict__ WvT,
           const float* __restrict__ bq, const float* __restrict__ bk,
           const float* __restrict__ bv, u16* __restrict__ QKV, u16* __restrict__ VT){
  __shared__ u16 ldsA[128 * 64];
  __shared__ u16 ldsB[128 * 64];
  const int mtile = blockIdx.x, ntile = blockIdx.y;
  const int sect = ntile >> 3, h = ntile & 7;
  const u16* Ag = xb + (size_t)mtile * 128 * 1024;
  const u16* WT = sect == 0 ? WqT : (sect == 1 ? WkT : WvT);
  const u16* Bg = WT + (size_t)h * 128 * 1024;
  f32x4 acc[4][4];
#pragma unroll
  for (int m = 0; m < 4; ++m)
#pragma unroll
    for (int n = 0; n < 4; ++n) acc[m][n] = f32x4{0.f, 0.f, 0.f, 0.f};
  core22(Ag, 1024, Bg, 1024, 16, ldsA, ldsB, acc);

  const int tid = threadIdx.x, lane = tid & 63, w = tid >> 6;
  const int wm = (w >> 1) * 64, wn = (w & 1) * 64;
  const float* bias = (sect == 0 ? bq : (sect == 1 ? bk : bv)) + h * 128;
  const int b  = (mtile * 128) >> 12;
  const int s0 = (mtile * 128) & 4095;
  const int bh = b * 8 + h;
#pragma unroll
  for (int m = 0; m < 4; ++m){
    const int r0 = wm + m * 16 + ((lane >> 4) << 2);
#pragma unroll
    for (int n = 0; n < 4; ++n){
      const int col = wn + n * 16 + (lane & 15);
      const float bc = bias[col];
      if (sect < 2){
#pragma unroll
        for (int j = 0; j < 4; ++j){
          size_t r = (size_t)mtile * 128 + r0 + j;
          QKV[r * 2048 + sect * 1024 + h * 128 + col] = f2b(acc[m][n][j] + bc);
        }
      } else {
        u16x4 pk;
#pragma unroll
        for (int j = 0; j < 4; ++j) pk[j] = f2b(acc[m][n][j] + bc);
        *(u16x4*)&VT[((size_t)bh * NKV + col) * 4096 + s0 + r0] = pk;
      }
    }
  }
}

// ---- K2b: phi. zp = Qhead @ omega; epilogue sin/cos. grid (128, 16) ----
__global__ __launch_bounds__(256, 2)
void k_phi(const u16* __restrict__ QKV, const u16* __restrict__ wT,
           u16* __restrict__ Qf, u16* __restrict__ KfT){
  __shared__ u16 ldsA[128 * 64];
  __shared__ u16 ldsB[128 * 64];
  const int mtile = blockIdx.x, hz = blockIdx.y;
  const int sect = hz >> 3, h = hz & 7;
  const u16* Ag = QKV + (size_t)mtile * 128 * 2048 + sect * 1024 + h * 128;
  f32x4 acc[4][4];
#pragma unroll
  for (int m = 0; m < 4; ++m)
#pragma unroll
    for (int n = 0; n < 4; ++n) acc[m][n] = f32x4{0.f, 0.f, 0.f, 0.f};
  core22(Ag, 2048, wT, 128, 2, ldsA, ldsB, acc);

  const int tid = threadIdx.x, lane = tid & 63, w = tid >> 6;
  const int wm = (w >> 1) * 64, wn = (w & 1) * 64;
  const int b  = (mtile * 128) >> 12;
  const int s0 = (mtile * 128) & 4095;
  const int bh = b * 8 + h;
#pragma unroll
  for (int m = 0; m < 4; ++m){
    const int r0 = wm + m * 16 + ((lane >> 4) << 2);
#pragma unroll
    for (int n = 0; n < 4; ++n){
      const int f = wn + n * 16 + (lane & 15);
      if (sect == 0){
#pragma unroll
        for (int j = 0; j < 4; ++j){
          float sv, cv; __sincosf(acc[m][n][j], &sv, &cv);
          size_t base = ((size_t)bh * 4096 + s0 + r0 + j) * 256;
          Qf[base + f]       = f2b(sv);
          Qf[base + 128 + f] = f2b(cv);
        }
      } else {
        u16x4 ps, pc;
#pragma unroll
        for (int j = 0; j < 4; ++j){
          float sv, cv; __sincosf(acc[m][n][j], &sv, &cv);
          ps[j] = f2b(sv); pc[j] = f2b(cv);
        }
        size_t sb = (size_t)s0 + r0;
        *(u16x4*)&KfT[((size_t)bh * 256 + f) * 4096 + sb]       = ps;
        *(u16x4*)&KfT[((size_t)bh * 256 + 128 + f) * 4096 + sb] = pc;
      }
    }
  }
}

// ---- K3: KV = Kf^T V (+Ksum via ones row). grid (2 mtiles, 32 bh, 4 ksplit) ----
__global__ __launch_bounds__(256, 2)
void k_kv(const u16* __restrict__ KfT, const u16* __restrict__ VT, float* __restrict__ part){
  __shared__ u16 ldsA[128 * 64];
  __shared__ u16 ldsB[NKV * 64];
  const int mtile = blockIdx.x, bh = blockIdx.y, ks = blockIdx.z;
  const u16* Ag = KfT + ((size_t)bh * 256 + mtile * 128) * 4096 + ks * 1024;
  const u16* Bg = VT + (size_t)bh * NKV * 4096 + ks * 1024;
  f32x4 acc[2][9];
#pragma unroll
  for (int m = 0; m < 2; ++m)
#pragma unroll
    for (int n = 0; n < 9; ++n) acc[m][n] = f32x4{0.f, 0.f, 0.f, 0.f};
  core41(Ag, 4096, Bg, 4096, 16, ldsA, ldsB, acc);

  const int tid = threadIdx.x, lane = tid & 63, w = tid >> 6;
#pragma unroll
  for (int m = 0; m < 2; ++m){
    const int mr = mtile * 128 + w * 32 + m * 16 + ((lane >> 4) << 2);
#pragma unroll
    for (int n = 0; n < 9; ++n){
      const int nn = n * 16 + (lane & 15);
      *(f32x4*)&part[(((size_t)ks * 32 + bh) * NKV + nn) * 256 + mr] = acc[m][n];
    }
  }
}

__global__ void k_kvred(const float* __restrict__ part, u16* __restrict__ KVT){
  const int total = 32 * NKV * 256;
  int idx = blockIdx.x * blockDim.x + threadIdx.x;
  if (idx >= total) return;
  float v = 0.f;
#pragma unroll
  for (int p = 0; p < 4; ++p) v += part[(size_t)p * total + idx];
  KVT[idx] = f2b(v);
}

// ---- K5: out = (Qf @ KV) / denom. grid (32 mtiles, 32 bh) ----
__global__ __launch_bounds__(256, 2)
void k_attn(const u16* __restrict__ Qf, const u16* __restrict__ KVT, u16* __restrict__ att){
  __shared__ u16 ldsA[128 * 64];
  __shared__ u16 ldsB[NKV * 64];
  const int mtile = blockIdx.x, bh = blockIdx.y;
  const u16* Ag = Qf + ((size_t)bh * 4096 + mtile * 128) * 256;
  const u16* Bg = KVT + (size_t)bh * NKV * 256;
  f32x4 acc[2][9];
#pragma unroll
  for (int m = 0; m < 2; ++m)
#pragma unroll
    for (int n = 0; n < 9; ++n) acc[m][n] = f32x4{0.f, 0.f, 0.f, 0.f};
  core41(Ag, 256, Bg, 256, 4, ldsA, ldsB, acc);

  const int tid = threadIdx.x, lane = tid & 63, w = tid >> 6;
  const int b = bh >> 3, h = bh & 7;
#pragma unroll
  for (int m = 0; m < 2; ++m){
    const int r0 = mtile * 128 + w * 32 + m * 16 + ((lane >> 4) << 2);
    float rden[4];
#pragma unroll
    for (int j = 0; j < 4; ++j){
      float d = __shfl(acc[m][8][j], lane & 48, 64);
      rden[j] = 1.f / (d + 1e-6f);
    }
#pragma unroll
    for (int n = 0; n < 8; ++n){
      const int dcol = n * 16 + (lane & 15);
#pragma unroll
      for (int j = 0; j < 4; ++j)
        att[((size_t)b * 4096 + r0 + j) * 1024 + h * 128 + dcol] = f2b(acc[m][n][j] * rden[j]);
    }
  }
}

// ---- K6: final projection. grid (128, 8) ----
__global__ __launch_bounds__(256, 2)
void k_out(const u16* __restrict__ att, const u16* __restrict__ WoT,
           const float* __restrict__ bo, float* __restrict__ out){
  __shared__ u16 ldsA[128 * 64];
  __shared__ u16 ldsB[128 * 64];
  const int mtile = blockIdx.x, ntile = blockIdx.y;
  const u16* Ag = att + (size_t)mtile * 128 * 1024;
  const u16* Bg = WoT + (size_t)ntile * 128 * 1024;
  f32x4 acc[4][4];
#pragma unroll
  for (int m = 0; m < 4; ++m)
#pragma unroll
    for (int n = 0; n < 4; ++n) acc[m][n] = f32x4{0.f, 0.f, 0.f, 0.f};
  core22(Ag, 1024, Bg, 1024, 16, ldsA, ldsB, acc);

  const int tid = threadIdx.x, lane = tid & 63, w = tid >> 6;
  const int wm = (w >> 1) * 64, wn = (w & 1) * 64;
#pragma unroll
  for (int m = 0; m < 4; ++m){
    const int rg = mtile * 128 + wm + m * 16 + ((lane >> 4) << 2);
#pragma unroll
    for (int n = 0; n < 4; ++n){
      const int c = ntile * 128 + wn + n * 16 + (lane & 15);
      const float bc = bo[c];
#pragma unroll
      for (int j = 0; j < 4; ++j)
        out[(size_t)(rg + j) * 1024 + c] = acc[m][n][j] + bc;
    }
  }
}

extern "C" void kernel_launch(void* const* d_in, const int* in_sizes, int n_in,
                              void* d_out, int out_size, void* d_ws, size_t ws_size,
                              hipStream_t stream){
  const float* x  = (const float*)d_in[0];
  const float* Wq = (const float*)d_in[1];
  const float* bq = (const float*)d_in[2];
  const float* Wk = (const float*)d_in[3];
  const float* bk = (const float*)d_in[4];
  const float* Wv = (const float*)d_in[5];
  const float* bv = (const float*)d_in[6];
  const float* Wo = (const float*)d_in[7];
  const float* bo = (const float*)d_in[8];
  const float* om = (const float*)d_in[9];
  float* out = (float*)d_out;
  char* ws = (char*)d_ws;

  // layout (bytes). xb aliases KfT (dead before KfT written); att/part/KVT alias QKV.
  const size_t OFF_KFT = 0;            // 64 MiB : KfT [32][256][4096] bf16
  const size_t OFF_XB  = 0;            // 32 MiB : xb  [16384][1024]  bf16 (alias)
  const size_t OFF_QKV = 67108864;     // 64 MiB : QKV [16384][2048]  bf16
  const size_t OFF_ATT = 67108864;     // 32 MiB : att [16384][1024]  bf16 (alias)
  const size_t OFF_PART= 100663296;    // 18 MiB : part [4][32][144][256] f32 (alias)
  const size_t OFF_KVT = 119537664;    // 2.25MiB: KVT [32][144][256] bf16 (alias)
  const size_t OFF_QF  = 134217728;    // 64 MiB : Qf  [32][4096][256] bf16
  const size_t OFF_VT  = 201326592;    // 36 MiB : VT  [32][144][4096] bf16
  const size_t OFF_WQT = 239075328;    // 4 x 2 MiB + 32 KiB weights
  const size_t OFF_WKT = OFF_WQT + 2097152;
  const size_t OFF_WVT = OFF_WKT + 2097152;
  const size_t OFF_WOT = OFF_WVT + 2097152;
  const size_t OFF_WT  = OFF_WOT + 2097152;
  const size_t NEEDED  = OFF_WT + 32768;
  if (ws_size < NEEDED) return;  // insufficient scratch: fail loudly (output stays poisoned)

  u16* xb  = (u16*)(ws + OFF_XB);
  u16* WqT = (u16*)(ws + OFF_WQT);
  u16* WkT = (u16*)(ws + OFF_WKT);
  u16* WvT = (u16*)(ws + OFF_WVT);
  u16* WoT = (u16*)(ws + OFF_WOT);
  u16* wT  = (u16*)(ws + OFF_WT);
  u16* QKV = (u16*)(ws + OFF_QKV);
  u16* VT  = (u16*)(ws + OFF_VT);
  u16* Qf  = (u16*)(ws + OFF_QF);
  u16* KfT = (u16*)(ws + OFF_KFT);
  float* part = (float*)(ws + OFF_PART);
  u16* KVT = (u16*)(ws + OFF_KVT);
  u16* att = (u16*)(ws + OFF_ATT);

  k_cast<<<dim3(2048), dim3(256), 0, stream>>>(x, xb, 16384 * 1024 / 4);
  k_tc<<<dim3(16, 16), dim3(256), 0, stream>>>(Wq, WqT, 1024, 1024);
  k_tc<<<dim3(16, 16), dim3(256), 0, stream>>>(Wk, WkT, 1024, 1024);
  k_tc<<<dim3(16, 16), dim3(256), 0, stream>>>(Wv, WvT, 1024, 1024);
  k_tc<<<dim3(16, 16), dim3(256), 0, stream>>>(Wo, WoT, 1024, 1024);
  k_tc<<<dim3(2, 2), dim3(256), 0, stream>>>(om, wT, 128, 128);
  k_vtinit<<<dim3(1024), dim3(256), 0, stream>>>(VT);

  k_qkv<<<dim3(128, 24), dim3(256), 0, stream>>>(xb, WqT, WkT, WvT, bq, bk, bv, QKV, VT);
  k_phi<<<dim3(128, 16), dim3(256), 0, stream>>>(QKV, wT, Qf, KfT);
  k_kv<<<dim3(2, 32, 4), dim3(256), 0, stream>>>(KfT, VT, part);
  k_kvred<<<dim3(32 * NKV * 256 / 256), dim3(256), 0, stream>>>(part, KVT);
  k_attn<<<dim3(32, 32), dim3(256), 0, stream>>>(Qf, KVT, att);
  k_out<<<dim3(128, 8), dim3(256), 0, stream>>>(att, WoT, bo, out);
}